// Round 4
// baseline (167.079 us; speedup 1.0000x reference)
//
#include <hip/hip_runtime.h>

#define PAD_V 8192
#define H1 512
#define H2 64
#define B_SZ 32
#define K_SZ 32
#define L_SZ 128
#define EMB4_BLOCKS ((B_SZ + B_SZ * K_SZ) / 4)   // 264: 4 bags per block
#define ISECT_BLOCKS ((B_SZ * K_SZ) / 4)         // 256: 4 (b,k) pairs per block

// ---------------------------------------------------------------------------
// Kernel 1 (front): two roles by blockIdx.
//  - blocks 0..263: FOUR bags each (blocks 0..7 query, 8..263 poi).
//    R5 change: quarter-block owns one bag end-to-end for the gather (no
//    cross-quarter s_red reduction, one fewer barrier), and the MLP loads
//    each W1/W2 row-chunk ONCE and applies it to all 4 bags -> weight
//    traffic 152 MB -> 38 MB. Grid 1312 -> 520 blocks (all co-resident).
//  - blocks 264..519: bitmap intersection + hit compaction (unchanged).
// NOTE (R4 post-mortem): no device-scope done-counter fusion — 1024
// simultaneous device atomics + threadfence cost +22 us.
// ---------------------------------------------------------------------------
__global__ __launch_bounds__(512, 6) void front_kernel(
    const int* __restrict__ qbf, const int* __restrict__ pbf,
    const float* __restrict__ codebook,
    const float* __restrict__ qW1, const float* __restrict__ qb1,
    const float* __restrict__ qW2, const float* __restrict__ qb2,
    const float* __restrict__ pW1, const float* __restrict__ pb1,
    const float* __restrict__ pW2, const float* __restrict__ pb2,
    const float* __restrict__ qa0p, const float* __restrict__ qa1p, const float* __restrict__ qa2p,
    const float* __restrict__ pa0p, const float* __restrict__ pa1p, const float* __restrict__ pa2p,
    float* __restrict__ qh_out, float* __restrict__ ph_out,
    int* __restrict__ nh_ws, int* __restrict__ hits_ws)
{
    const int tid = threadIdx.x;

    // ---- role B: intersection blocks (unchanged) ----
    if (blockIdx.x >= EMB4_BLOCKS) {
        __shared__ unsigned int bm4[4][256];   // 4 KB
        __shared__ int s_nh4[4];
        __shared__ int s_hit4[4][L_SZ];        // 2 KB

        const int pair0 = (blockIdx.x - EMB4_BLOCKS) * 4;
        const int sub = tid >> 7;              // 0..3
        const int t   = tid & 127;
        const int pair = pair0 + sub;
        const int b = pair >> 5;

        bm4[sub][t] = 0u; bm4[sub][t + 128] = 0u;
        if (t == 0) s_nh4[sub] = 0;
        __syncthreads();

        int pv = pbf[pair * L_SZ + t];
        if ((unsigned)pv < (unsigned)PAD_V)
            atomicOr(&bm4[sub][pv >> 5], 1u << (pv & 31));
        __syncthreads();

        int v = qbf[b * L_SZ + t];
        bool hit = ((unsigned)v < (unsigned)PAD_V) &&
                   ((bm4[sub][v >> 5] >> (v & 31)) & 1u);
        if (hit) {
            int pos = atomicAdd(&s_nh4[sub], 1);
            s_hit4[sub][pos] = v;
        }
        __syncthreads();

        if (t == 0) nh_ws[pair] = s_nh4[sub];
        if (t < s_nh4[sub]) hits_ws[pair * L_SZ + t] = s_hit4[sub][t];
        return;
    }

    // ---- role A: embedding + MLP, 4 bags per block ----
    __shared__ int   s_idx[4][L_SZ];      // 2 KB
    __shared__ int   s_cntw[8];
    __shared__ float s_x[4][H1];          // 8 KB
    __shared__ float s_p1[4][32][H2];     // 32 KB
    __shared__ float s_h1[4][H2];         // 1 KB

    const bool is_q = (blockIdx.x < (B_SZ / 4));
    const int* idx_base;
    int bag0;
    const float *W1, *b1, *W2, *b2;
    float a0, a1, a2;
    float* out;
    if (is_q) {
        idx_base = qbf; bag0 = blockIdx.x * 4;
        W1 = qW1; b1 = qb1; W2 = qW2; b2 = qb2;
        a0 = *qa0p; a1 = *qa1p; a2 = *qa2p;
        out = qh_out;
    } else {
        idx_base = pbf; bag0 = (blockIdx.x - (B_SZ / 4)) * 4;
        W1 = pW1; b1 = pb1; W2 = pW2; b2 = pb2;
        a0 = *pa0p; a1 = *pa1p; a2 = *pa2p;
        out = ph_out;
    }

    const int sub = tid >> 7;   // quarter = local bag 0..3
    const int t   = tid & 127;  // 16B chunk within row / index position

    {
        int v = idx_base[(bag0 + sub) * L_SZ + t];
        s_idx[sub][t] = v;
        unsigned long long bal = __ballot(v != PAD_V);
        if ((tid & 63) == 0) s_cntw[tid >> 6] = __popcll(bal);
    }
    __syncthreads();

    // gather: quarter `sub` owns bag `sub`; thread t accumulates chunk t over
    // all 128 rows. No cross-quarter reduction needed.
    {
        const float4* cb4 = (const float4*)codebook;
        float ax = 0.f, ay = 0.f, az = 0.f, aw = 0.f;
        #pragma unroll 8
        for (int l = 0; l < L_SZ; l++) {
            int u = s_idx[sub][l];
            float m = (u != PAD_V) ? 1.0f : 0.0f;
            float4 r = cb4[(size_t)u * 128 + t];
            ax = fmaf(m, r.x, ax);
            ay = fmaf(m, r.y, ay);
            az = fmaf(m, r.z, az);
            aw = fmaf(m, r.w, aw);
        }
        int cnt = s_cntw[2 * sub] + s_cntw[2 * sub + 1];
        float inv = (cnt > 0) ? 1.0f / (float)cnt : 0.0f;
        float e0 = ax * inv, e1 = ay * inv, e2 = az * inv, e3 = aw * inv;
        s_x[sub][4 * t + 0] = (e0 >= 0.f) ? e0 : a0 * e0;
        s_x[sub][4 * t + 1] = (e1 >= 0.f) ? e1 : a0 * e1;
        s_x[sub][4 * t + 2] = (e2 >= 0.f) ? e2 : a0 * e2;
        s_x[sub][4 * t + 3] = (e3 >= 0.f) ? e3 : a0 * e3;
    }
    __syncthreads();

    const int j4 = tid & 15;   // col quad
    const int ch = tid >> 4;   // 0..31 i-chunk

    // layer 1: each W1 row-chunk loaded once, applied to 4 bags
    {
        const float4* W1v = (const float4*)W1;
        const int i0 = ch * 16;
        float4 A0 = make_float4(0.f,0.f,0.f,0.f);
        float4 A1 = make_float4(0.f,0.f,0.f,0.f);
        float4 A2 = make_float4(0.f,0.f,0.f,0.f);
        float4 A3 = make_float4(0.f,0.f,0.f,0.f);
        #pragma unroll 8
        for (int i = 0; i < 16; i++) {
            float4 w = W1v[(size_t)(i0 + i) * 16 + j4];
            float x0 = s_x[0][i0 + i];
            float x1 = s_x[1][i0 + i];
            float x2 = s_x[2][i0 + i];
            float x3 = s_x[3][i0 + i];
            A0.x = fmaf(x0, w.x, A0.x); A0.y = fmaf(x0, w.y, A0.y);
            A0.z = fmaf(x0, w.z, A0.z); A0.w = fmaf(x0, w.w, A0.w);
            A1.x = fmaf(x1, w.x, A1.x); A1.y = fmaf(x1, w.y, A1.y);
            A1.z = fmaf(x1, w.z, A1.z); A1.w = fmaf(x1, w.w, A1.w);
            A2.x = fmaf(x2, w.x, A2.x); A2.y = fmaf(x2, w.y, A2.y);
            A2.z = fmaf(x2, w.z, A2.z); A2.w = fmaf(x2, w.w, A2.w);
            A3.x = fmaf(x3, w.x, A3.x); A3.y = fmaf(x3, w.y, A3.y);
            A3.z = fmaf(x3, w.z, A3.z); A3.w = fmaf(x3, w.w, A3.w);
        }
        s_p1[0][ch][4*j4+0] = A0.x; s_p1[0][ch][4*j4+1] = A0.y;
        s_p1[0][ch][4*j4+2] = A0.z; s_p1[0][ch][4*j4+3] = A0.w;
        s_p1[1][ch][4*j4+0] = A1.x; s_p1[1][ch][4*j4+1] = A1.y;
        s_p1[1][ch][4*j4+2] = A1.z; s_p1[1][ch][4*j4+3] = A1.w;
        s_p1[2][ch][4*j4+0] = A2.x; s_p1[2][ch][4*j4+1] = A2.y;
        s_p1[2][ch][4*j4+2] = A2.z; s_p1[2][ch][4*j4+3] = A2.w;
        s_p1[3][ch][4*j4+0] = A3.x; s_p1[3][ch][4*j4+1] = A3.y;
        s_p1[3][ch][4*j4+2] = A3.z; s_p1[3][ch][4*j4+3] = A3.w;
    }
    __syncthreads();
    if (tid < 256) {
        const int bg = tid >> 6, col = tid & 63;
        float s = b1[col];
        #pragma unroll
        for (int r = 0; r < 32; r++) s += s_p1[bg][r][col];
        s_h1[bg][col] = (s >= 0.f) ? s : a1 * s;
    }
    __syncthreads();

    // layer 2: same structure, 2 rows per chunk
    {
        const float4* W2v = (const float4*)W2;
        const int i0 = ch * 2;
        float4 A0 = make_float4(0.f,0.f,0.f,0.f);
        float4 A1 = make_float4(0.f,0.f,0.f,0.f);
        float4 A2 = make_float4(0.f,0.f,0.f,0.f);
        float4 A3 = make_float4(0.f,0.f,0.f,0.f);
        #pragma unroll
        for (int i = 0; i < 2; i++) {
            float4 w = W2v[(size_t)(i0 + i) * 16 + j4];
            float x0 = s_h1[0][i0 + i];
            float x1 = s_h1[1][i0 + i];
            float x2 = s_h1[2][i0 + i];
            float x3 = s_h1[3][i0 + i];
            A0.x = fmaf(x0, w.x, A0.x); A0.y = fmaf(x0, w.y, A0.y);
            A0.z = fmaf(x0, w.z, A0.z); A0.w = fmaf(x0, w.w, A0.w);
            A1.x = fmaf(x1, w.x, A1.x); A1.y = fmaf(x1, w.y, A1.y);
            A1.z = fmaf(x1, w.z, A1.z); A1.w = fmaf(x1, w.w, A1.w);
            A2.x = fmaf(x2, w.x, A2.x); A2.y = fmaf(x2, w.y, A2.y);
            A2.z = fmaf(x2, w.z, A2.z); A2.w = fmaf(x2, w.w, A2.w);
            A3.x = fmaf(x3, w.x, A3.x); A3.y = fmaf(x3, w.y, A3.y);
            A3.z = fmaf(x3, w.z, A3.z); A3.w = fmaf(x3, w.w, A3.w);
        }
        s_p1[0][ch][4*j4+0] = A0.x; s_p1[0][ch][4*j4+1] = A0.y;
        s_p1[0][ch][4*j4+2] = A0.z; s_p1[0][ch][4*j4+3] = A0.w;
        s_p1[1][ch][4*j4+0] = A1.x; s_p1[1][ch][4*j4+1] = A1.y;
        s_p1[1][ch][4*j4+2] = A1.z; s_p1[1][ch][4*j4+3] = A1.w;
        s_p1[2][ch][4*j4+0] = A2.x; s_p1[2][ch][4*j4+1] = A2.y;
        s_p1[2][ch][4*j4+2] = A2.z; s_p1[2][ch][4*j4+3] = A2.w;
        s_p1[3][ch][4*j4+0] = A3.x; s_p1[3][ch][4*j4+1] = A3.y;
        s_p1[3][ch][4*j4+2] = A3.z; s_p1[3][ch][4*j4+3] = A3.w;
    }
    __syncthreads();
    if (tid < 256) {
        const int bg = tid >> 6, col = tid & 63;
        float s = b2[col];
        #pragma unroll
        for (int r = 0; r < 32; r++) s += s_p1[bg][r][col];
        s = (s >= 0.f) ? s : a2 * s;
        out[(bag0 + bg) * H2 + col] = s;
    }
}

// ---------------------------------------------------------------------------
// Kernel 2 (fused): text-sim dots + row-max + sigmoid + distance epilogue.
// One block per b (1024 thr = 16 waves); wave w handles pairs w and w+16.
// ---------------------------------------------------------------------------
__global__ __launch_bounds__(1024) void sim_epilogue_kernel(
    const float* __restrict__ q_eval, const float* __restrict__ p_eval,
    const float* __restrict__ qh_ws, const float* __restrict__ ph_ws,
    const int* __restrict__ nh_ws, const int* __restrict__ hits_ws,
    const float* __restrict__ ind_ap,
    const float* __restrict__ qloc, const float* __restrict__ ploc,
    const float* __restrict__ ap, const float* __restrict__ bp,
    const float* __restrict__ cp, const float* __restrict__ dp,
    float* __restrict__ out)
{
    const int b    = blockIdx.x;
    const int tid  = threadIdx.x;
    const int wave = tid >> 6;
    const int lane = tid & 63;
    __shared__ float s_text[K_SZ];

    const float ind_a = *ind_ap;
    const float qh = qh_ws[b * H2 + lane];   // same for every k of this b

    for (int kk = wave; kk < K_SZ; kk += 16) {
        const int blk = b * K_SZ + kk;
        const float ph = ph_ws[blk * H2 + lane];
        const int   nh = nh_ws[blk];
        float local = 0.f;
        for (int hh = 0; hh < nh; hh++) {
            int v = hits_ws[blk * L_SZ + hh];
            float qd = qh * q_eval[(size_t)v * H2 + lane];
            float pd = ph * p_eval[(size_t)v * H2 + lane];
            #pragma unroll
            for (int m = 1; m < 64; m <<= 1) {
                qd += __shfl_xor(qd, m);
                pd += __shfl_xor(pd, m);
            }
            qd = (qd >= 0.f) ? qd : ind_a * qd;
            pd = (pd >= 0.f) ? pd : ind_a * pd;
            local += (qd + 1.f) * (pd + 1.f);
        }
        if (lane == 0) s_text[kk] = local;
    }
    __syncthreads();

    if (tid < K_SZ) {
        const int kk = tid;
        float ts_raw = s_text[kk];
        float mx = ts_raw;
        #pragma unroll
        for (int m = 1; m < 32; m <<= 1) mx = fmaxf(mx, __shfl_xor(mx, m));

        float qx = qloc[b * 2], qy = qloc[b * 2 + 1];
        float px = ploc[(b * K_SZ + kk) * 2];
        float py = ploc[(b * K_SZ + kk) * 2 + 1];
        float dx = qx - px, dy = qy - py;
        float dist = sqrtf(dx * dx + dy * dy);
        float ds = -logf(dist + 1.0f);

        float ts = (2.0f * ts_raw - mx) / (mx + 1e-6f);
        float A = *ap, Bb = *bp, C = *cp, D = *dp;
        float sig = 1.0f / (1.0f + expf(-(A * ts + Bb)));
        out[b * K_SZ + kk] = (C - sig) * (ds - D);
    }
}

extern "C" void kernel_launch(void* const* d_in, const int* in_sizes, int n_in,
                              void* d_out, int out_size, void* d_ws, size_t ws_size,
                              hipStream_t stream) {
    const int*   qbf      = (const int*)d_in[0];
    const int*   pbf      = (const int*)d_in[1];
    const float* qloc     = (const float*)d_in[2];
    const float* ploc     = (const float*)d_in[3];
    const float* codebook = (const float*)d_in[4];
    const float* qW1      = (const float*)d_in[5];
    const float* qb1      = (const float*)d_in[6];
    const float* qW2      = (const float*)d_in[7];
    const float* qb2      = (const float*)d_in[8];
    const float* pW1      = (const float*)d_in[9];
    const float* pb1      = (const float*)d_in[10];
    const float* pW2      = (const float*)d_in[11];
    const float* pb2      = (const float*)d_in[12];
    const float* q_eval   = (const float*)d_in[13];
    const float* p_eval   = (const float*)d_in[14];
    const float* qa0      = (const float*)d_in[15];
    const float* qa1      = (const float*)d_in[16];
    const float* qa2      = (const float*)d_in[17];
    const float* pa0      = (const float*)d_in[18];
    const float* pa1      = (const float*)d_in[19];
    const float* pa2      = (const float*)d_in[20];
    const float* ind_a    = (const float*)d_in[21];
    const float* a        = (const float*)d_in[22];
    const float* bsc      = (const float*)d_in[23];
    const float* c        = (const float*)d_in[24];
    const float* d        = (const float*)d_in[25];

    float* qh   = (float*)d_ws;                   // 32*64
    float* ph   = qh + B_SZ * H2;                 // 1024*64
    int*   nh   = (int*)(ph + B_SZ * K_SZ * H2);  // 1024
    int*   hits = nh + B_SZ * K_SZ;               // 1024*128

    front_kernel<<<EMB4_BLOCKS + ISECT_BLOCKS, 512, 0, stream>>>(
        qbf, pbf, codebook,
        qW1, qb1, qW2, qb2, pW1, pb1, pW2, pb2,
        qa0, qa1, qa2, pa0, pa1, pa2,
        qh, ph, nh, hits);

    sim_epilogue_kernel<<<B_SZ, 1024, 0, stream>>>(
        q_eval, p_eval, qh, ph, nh, hits, ind_a,
        qloc, ploc, a, bsc, c, d, (float*)d_out);
}

// Round 7
// 157.270 us; speedup vs baseline: 1.0624x; 1.0624x over previous
//
#include <hip/hip_runtime.h>

#define PAD_V 8192
#define H1 512
#define H2 64
#define B_SZ 32
#define K_SZ 32
#define L_SZ 128
#define EMB_BLOCKS (B_SZ + B_SZ * K_SZ)       // 1056
#define ISECT_BLOCKS ((B_SZ * K_SZ) / 4)      // 256: 4 (b,k) pairs per block

// ---------------------------------------------------------------------------
// Kernel 1 (front): two roles by blockIdx.
//  - blocks 0..1055: one bag each (R6: reverted from 4-bag — R5 post-mortem:
//    4-bag cut gather concurrency 4x (264 blocks, Occ 16%, VALUBusy 9%) and
//    the weight "savings" were L2 hits anyway (<600 KB fits every XCD L2).
//    front went <42 -> 45 us, total 155 -> 167).
//    R6 change: gather loads explicitly batched 8-deep into a register
//    array + __launch_bounds__(512,4) for VGPR headroom — R5 counters
//    showed VGPR_Count=40, i.e. ~2 loads in flight -> 2.4 TB/s effective.
//  - blocks 1056..1311: bitmap intersection + hit compaction.
// NOTE (R4 post-mortem): no device-scope done-counter fusion — 1024
// simultaneous device atomics + threadfence cost +22 us.
// ---------------------------------------------------------------------------
__global__ __launch_bounds__(512, 4) void front_kernel(
    const int* __restrict__ qbf, const int* __restrict__ pbf,
    const float* __restrict__ codebook,
    const float* __restrict__ qW1, const float* __restrict__ qb1,
    const float* __restrict__ qW2, const float* __restrict__ qb2,
    const float* __restrict__ pW1, const float* __restrict__ pb1,
    const float* __restrict__ pW2, const float* __restrict__ pb2,
    const float* __restrict__ qa0p, const float* __restrict__ qa1p, const float* __restrict__ qa2p,
    const float* __restrict__ pa0p, const float* __restrict__ pa1p, const float* __restrict__ pa2p,
    float* __restrict__ qh_out, float* __restrict__ ph_out,
    int* __restrict__ nh_ws, int* __restrict__ hits_ws)
{
    const int tid = threadIdx.x;

    // ---- role B: intersection blocks ----
    if (blockIdx.x >= EMB_BLOCKS) {
        __shared__ unsigned int bm4[4][256];   // 4 KB
        __shared__ int s_nh4[4];
        __shared__ int s_hit4[4][L_SZ];        // 2 KB

        const int pair0 = (blockIdx.x - EMB_BLOCKS) * 4;
        const int sub = tid >> 7;              // 0..3
        const int t   = tid & 127;
        const int pair = pair0 + sub;
        const int b = pair >> 5;

        bm4[sub][t] = 0u; bm4[sub][t + 128] = 0u;
        if (t == 0) s_nh4[sub] = 0;
        __syncthreads();

        int pv = pbf[pair * L_SZ + t];
        if ((unsigned)pv < (unsigned)PAD_V)
            atomicOr(&bm4[sub][pv >> 5], 1u << (pv & 31));
        __syncthreads();

        int v = qbf[b * L_SZ + t];
        bool hit = ((unsigned)v < (unsigned)PAD_V) &&
                   ((bm4[sub][v >> 5] >> (v & 31)) & 1u);
        if (hit) {
            int pos = atomicAdd(&s_nh4[sub], 1);
            s_hit4[sub][pos] = v;
        }
        __syncthreads();

        if (t == 0) nh_ws[pair] = s_nh4[sub];
        if (t < s_nh4[sub]) hits_ws[pair * L_SZ + t] = s_hit4[sub][t];
        return;
    }

    // ---- role A: embedding + MLP ----
    const bool is_q = (blockIdx.x < B_SZ);
    const int* idx_base;
    int bag;
    const float *W1, *b1, *W2, *b2;
    float a0, a1, a2;
    float* out;
    if (is_q) {
        idx_base = qbf; bag = blockIdx.x;
        W1 = qW1; b1 = qb1; W2 = qW2; b2 = qb2;
        a0 = *qa0p; a1 = *qa1p; a2 = *qa2p;
        out = qh_out;
    } else {
        idx_base = pbf; bag = blockIdx.x - B_SZ;
        W1 = pW1; b1 = pb1; W2 = pW2; b2 = pb2;
        a0 = *pa0p; a1 = *pa1p; a2 = *pa2p;
        out = ph_out;
    }

    __shared__ int   s_idx[L_SZ];
    __shared__ int   s_cntp[2];
    __shared__ float s_red[3][L_SZ][4];   // 6 KB
    __shared__ float s_x[H1];             // 2 KB
    __shared__ float s_p1[32][H2];        // 8 KB
    __shared__ float s_h1[H2];

    if (tid < L_SZ) s_idx[tid] = idx_base[bag * L_SZ + tid];
    __syncthreads();

    if (tid < L_SZ) {
        unsigned long long bal = __ballot(s_idx[tid] != PAD_V);
        if ((tid & 63) == 0) s_cntp[tid >> 6] = __popcll(bal);
    }

    // gather: quarter q = tid>>7 owns 32 rows; g = tid&127 is the 16B chunk.
    // R6: explicit 8-deep batching — idx[8]/buf[8] register arrays force 8
    // global_load_dwordx4 in flight per thread (R5: only ~2 at VGPR=40).
    const int g = tid & 127;
    const int q = tid >> 7;
    const float4* cb4 = (const float4*)codebook;
    float ax = 0.f, ay = 0.f, az = 0.f, aw = 0.f;
    {
        int   idx[8];
        float4 buf[8];
        #pragma unroll
        for (int batch = 0; batch < 4; batch++) {
            #pragma unroll
            for (int j = 0; j < 8; j++) idx[j] = s_idx[q * 32 + batch * 8 + j];
            #pragma unroll
            for (int j = 0; j < 8; j++) buf[j] = cb4[(size_t)idx[j] * 128 + g];
            #pragma unroll
            for (int j = 0; j < 8; j++) {
                float m = (idx[j] != PAD_V) ? 1.0f : 0.0f;
                ax = fmaf(m, buf[j].x, ax);
                ay = fmaf(m, buf[j].y, ay);
                az = fmaf(m, buf[j].z, az);
                aw = fmaf(m, buf[j].w, aw);
            }
        }
    }
    if (q != 0) {
        s_red[q - 1][g][0] = ax; s_red[q - 1][g][1] = ay;
        s_red[q - 1][g][2] = az; s_red[q - 1][g][3] = aw;
    }
    __syncthreads();
    if (q == 0) {
        int cnt = s_cntp[0] + s_cntp[1];
        float inv = (cnt > 0) ? 1.0f / (float)cnt : 0.0f;
        float e0 = (ax + s_red[0][g][0] + s_red[1][g][0] + s_red[2][g][0]) * inv;
        float e1 = (ay + s_red[0][g][1] + s_red[1][g][1] + s_red[2][g][1]) * inv;
        float e2 = (az + s_red[0][g][2] + s_red[1][g][2] + s_red[2][g][2]) * inv;
        float e3 = (aw + s_red[0][g][3] + s_red[1][g][3] + s_red[2][g][3]) * inv;
        s_x[4 * g + 0] = (e0 >= 0.f) ? e0 : a0 * e0;
        s_x[4 * g + 1] = (e1 >= 0.f) ? e1 : a0 * e1;
        s_x[4 * g + 2] = (e2 >= 0.f) ? e2 : a0 * e2;
        s_x[4 * g + 3] = (e3 >= 0.f) ? e3 : a0 * e3;
    }
    __syncthreads();

    // layer 1: thread = (i-chunk ch = tid>>4 of 32, col-quad j4 = tid&15)
    // 16 i's per chunk, float4 weight loads (cols 4*j4..4*j4+3)
    const int j4 = tid & 15;
    const int ch = tid >> 4;
    const float4* W1v = (const float4*)W1;
    {
        const int i0 = ch * 16;
        float sx = 0.f, sy = 0.f, sz = 0.f, sw = 0.f;
        #pragma unroll
        for (int i = 0; i < 16; i++) {
            float x = s_x[i0 + i];
            float4 w = W1v[(size_t)(i0 + i) * 16 + j4];
            sx = fmaf(x, w.x, sx);
            sy = fmaf(x, w.y, sy);
            sz = fmaf(x, w.z, sz);
            sw = fmaf(x, w.w, sw);
        }
        s_p1[ch][4 * j4 + 0] = sx;
        s_p1[ch][4 * j4 + 1] = sy;
        s_p1[ch][4 * j4 + 2] = sz;
        s_p1[ch][4 * j4 + 3] = sw;
    }
    __syncthreads();
    if (tid < H2) {
        float s = b1[tid];
        #pragma unroll
        for (int r = 0; r < 32; r++) s += s_p1[r][tid];
        s_h1[tid] = (s >= 0.f) ? s : a1 * s;
    }
    __syncthreads();

    // layer 2: 32 chunks x 2 i's, float4 weight loads
    const float4* W2v = (const float4*)W2;
    {
        const int i0 = ch * 2;
        float sx = 0.f, sy = 0.f, sz = 0.f, sw = 0.f;
        #pragma unroll
        for (int i = 0; i < 2; i++) {
            float x = s_h1[i0 + i];
            float4 w = W2v[(size_t)(i0 + i) * 16 + j4];
            sx = fmaf(x, w.x, sx);
            sy = fmaf(x, w.y, sy);
            sz = fmaf(x, w.z, sz);
            sw = fmaf(x, w.w, sw);
        }
        s_p1[ch][4 * j4 + 0] = sx;
        s_p1[ch][4 * j4 + 1] = sy;
        s_p1[ch][4 * j4 + 2] = sz;
        s_p1[ch][4 * j4 + 3] = sw;
    }
    __syncthreads();
    if (tid < H2) {
        float s = b2[tid];
        #pragma unroll
        for (int r = 0; r < 32; r++) s += s_p1[r][tid];
        s = (s >= 0.f) ? s : a2 * s;
        out[bag * H2 + tid] = s;
    }
}

// ---------------------------------------------------------------------------
// Kernel 2: one wave per (b,k). Pure dot phase over precompacted hits.
// (R6: reverted from 32-block fused version — latency-bound phase needs the
// 1024-block spread across CUs, fusion used only 32/256 CUs.)
// ---------------------------------------------------------------------------
__global__ __launch_bounds__(64) void text_sim_kernel(
    const float* __restrict__ q_eval, const float* __restrict__ p_eval,
    const float* __restrict__ qh_ws, const float* __restrict__ ph_ws,
    const int* __restrict__ nh_ws, const int* __restrict__ hits_ws,
    const float* __restrict__ ind_ap,
    float* __restrict__ text_out)
{
    const int blk = blockIdx.x;      // (b,k) pair
    const int b    = blk >> 5;
    const int lane = threadIdx.x;    // 0..63

    const float qh = qh_ws[b * H2 + lane];
    const float ph = ph_ws[blk * H2 + lane];
    const int   nh = nh_ws[blk];
    const float ind_a = *ind_ap;

    float local = 0.f;
    for (int hh = 0; hh < nh; hh++) {
        int v = hits_ws[blk * L_SZ + hh];
        float qd = qh * q_eval[(size_t)v * H2 + lane];
        float pd = ph * p_eval[(size_t)v * H2 + lane];
        #pragma unroll
        for (int m = 1; m < 64; m <<= 1) {
            qd += __shfl_xor(qd, m);
            pd += __shfl_xor(pd, m);
        }
        qd = (qd >= 0.f) ? qd : ind_a * qd;
        pd = (pd >= 0.f) ? pd : ind_a * pd;
        local += (qd + 1.f) * (pd + 1.f);
    }
    if (lane == 0) text_out[blk] = local;
}

// ---------------------------------------------------------------------------
// Kernel 3: epilogue — one block per b: max, normalize, sigmoid, distance.
// ---------------------------------------------------------------------------
__global__ __launch_bounds__(64) void epilogue_kernel(
    const float* __restrict__ text_ws,
    const float* __restrict__ qloc, const float* __restrict__ ploc,
    const float* __restrict__ ap, const float* __restrict__ bp,
    const float* __restrict__ cp, const float* __restrict__ dp,
    float* __restrict__ out)
{
    const int b = blockIdx.x;
    const int t = threadIdx.x;
    const int kk = t & 31;

    float ts_raw = text_ws[b * K_SZ + kk];
    float mx = ts_raw;
    #pragma unroll
    for (int m = 1; m < 32; m <<= 1) mx = fmaxf(mx, __shfl_xor(mx, m));

    float qx = qloc[b * 2], qy = qloc[b * 2 + 1];
    float px = ploc[(b * K_SZ + kk) * 2];
    float py = ploc[(b * K_SZ + kk) * 2 + 1];
    float dx = qx - px, dy = qy - py;
    float dist = sqrtf(dx * dx + dy * dy);
    float ds = -logf(dist + 1.0f);

    float ts = (2.0f * ts_raw - mx) / (mx + 1e-6f);
    float A = *ap, Bb = *bp, C = *cp, D = *dp;
    float sig = 1.0f / (1.0f + expf(-(A * ts + Bb)));
    if (t < 32) out[b * K_SZ + kk] = (C - sig) * (ds - D);
}

extern "C" void kernel_launch(void* const* d_in, const int* in_sizes, int n_in,
                              void* d_out, int out_size, void* d_ws, size_t ws_size,
                              hipStream_t stream) {
    const int*   qbf      = (const int*)d_in[0];
    const int*   pbf      = (const int*)d_in[1];
    const float* qloc     = (const float*)d_in[2];
    const float* ploc     = (const float*)d_in[3];
    const float* codebook = (const float*)d_in[4];
    const float* qW1      = (const float*)d_in[5];
    const float* qb1      = (const float*)d_in[6];
    const float* qW2      = (const float*)d_in[7];
    const float* qb2      = (const float*)d_in[8];
    const float* pW1      = (const float*)d_in[9];
    const float* pb1      = (const float*)d_in[10];
    const float* pW2      = (const float*)d_in[11];
    const float* pb2      = (const float*)d_in[12];
    const float* q_eval   = (const float*)d_in[13];
    const float* p_eval   = (const float*)d_in[14];
    const float* qa0      = (const float*)d_in[15];
    const float* qa1      = (const float*)d_in[16];
    const float* qa2      = (const float*)d_in[17];
    const float* pa0      = (const float*)d_in[18];
    const float* pa1      = (const float*)d_in[19];
    const float* pa2      = (const float*)d_in[20];
    const float* ind_a    = (const float*)d_in[21];
    const float* a        = (const float*)d_in[22];
    const float* bsc      = (const float*)d_in[23];
    const float* c        = (const float*)d_in[24];
    const float* d        = (const float*)d_in[25];

    float* qh   = (float*)d_ws;                   // 32*64
    float* ph   = qh + B_SZ * H2;                 // 1024*64
    float* text = ph + B_SZ * K_SZ * H2;          // 1024
    int*   nh   = (int*)(text + B_SZ * K_SZ);     // 1024
    int*   hits = nh + B_SZ * K_SZ;               // 1024*128

    front_kernel<<<EMB_BLOCKS + ISECT_BLOCKS, 512, 0, stream>>>(
        qbf, pbf, codebook,
        qW1, qb1, qW2, qb2, pW1, pb1, pW2, pb2,
        qa0, qa1, qa2, pa0, pa1, pa2,
        qh, ph, nh, hits);

    text_sim_kernel<<<B_SZ * K_SZ, 64, 0, stream>>>(
        q_eval, p_eval, qh, ph, nh, hits, ind_a, text);

    epilogue_kernel<<<B_SZ, 64, 0, stream>>>(
        text, qloc, ploc, a, bsc, c, d, (float*)d_out);
}

// Round 10
// 145.163 us; speedup vs baseline: 1.1510x; 1.0834x over previous
//
#include <hip/hip_runtime.h>

#define PAD_V 8192
#define H1 512
#define H2 64
#define B_SZ 32
#define K_SZ 32
#define L_SZ 128
#define NBAGS (B_SZ + B_SZ * K_SZ)            // 1056
#define NSLICE 8                              // codebook column slices (1 per XCD)
#define GATHER_BLOCKS (NBAGS * NSLICE)        // 8448
#define ISECT2_BLOCKS ((B_SZ * K_SZ) / 2)     // 512: 2 (b,k) pairs per 256-thr block

// ---------------------------------------------------------------------------
// R7 restructure. R5/R6 post-mortems: gather is NOT MLP-limited (R6: 8-deep
// batching + 4x blocks = null). It is L2-miss-path limited: per-XCD L2 (4MB)
// holds 24% of the 16.8MB codebook -> 105MB L2-miss at ~2.5 TB/s = ~40us.
// Fix: column-slice the gather. slice = blockIdx % 8 -> (assumed) XCD
// round-robin means XCD s only touches codebook cols [s*64, s*64+64) =
// 2.1MB, fully L2-resident. All 270MB of demand becomes L2 hits.
// Embedding assembled via ws round-trip (2.2MB); MLP moved to kernel 2.
// ---------------------------------------------------------------------------

// Kernel 1: column-sliced gather (+ intersection role).
__global__ __launch_bounds__(256, 4) void gather_kernel(
    const int* __restrict__ qbf, const int* __restrict__ pbf,
    const float* __restrict__ codebook,
    const float* __restrict__ qa0p, const float* __restrict__ pa0p,
    float* __restrict__ x_ws,
    int* __restrict__ nh_ws, int* __restrict__ hits_ws)
{
    const int tid = threadIdx.x;

    // ---- role B: intersection (2 pairs per 256-thr block) ----
    if (blockIdx.x >= GATHER_BLOCKS) {
        __shared__ unsigned int bm2[2][256];   // 2 KB
        __shared__ int s_nh2[2];
        __shared__ int s_hit2[2][L_SZ];        // 1 KB

        const int pair0 = (blockIdx.x - GATHER_BLOCKS) * 2;
        const int sub = tid >> 7;              // 0..1
        const int t   = tid & 127;
        const int pair = pair0 + sub;
        const int b = pair >> 5;

        bm2[sub][t] = 0u; bm2[sub][t + 128] = 0u;
        if (t == 0) s_nh2[sub] = 0;
        __syncthreads();

        int pv = pbf[pair * L_SZ + t];
        if ((unsigned)pv < (unsigned)PAD_V)
            atomicOr(&bm2[sub][pv >> 5], 1u << (pv & 31));
        __syncthreads();

        int v = qbf[b * L_SZ + t];
        bool hit = ((unsigned)v < (unsigned)PAD_V) &&
                   ((bm2[sub][v >> 5] >> (v & 31)) & 1u);
        if (hit) {
            int pos = atomicAdd(&s_nh2[sub], 1);
            s_hit2[sub][pos] = v;
        }
        __syncthreads();

        if (t == 0) nh_ws[pair] = s_nh2[sub];
        if (t < s_nh2[sub]) hits_ws[pair * L_SZ + t] = s_hit2[sub][t];
        return;
    }

    // ---- role A: gather one (bag, slice) -> 64 embedding dims ----
    // slice = blockIdx % 8 so each XCD sees a fixed 2.1MB codebook column set.
    const int slice = blockIdx.x & (NSLICE - 1);
    const int bag   = blockIdx.x >> 3;          // 0..1055
    const bool is_q = (bag < B_SZ);
    const int* idx_base = is_q ? qbf : pbf;
    const int  bagl     = is_q ? bag : (bag - B_SZ);
    const float a0      = is_q ? *qa0p : *pa0p;

    __shared__ int   s_idx[L_SZ];
    __shared__ int   s_cnt[2];
    __shared__ float4 s_part[16][16];           // 4 KB

    if (tid < L_SZ) {
        int v = idx_base[bagl * L_SZ + tid];
        s_idx[tid] = v;
        unsigned long long bal = __ballot(v != PAD_V);
        if ((tid & 63) == 0) s_cnt[tid >> 6] = __popcll(bal);
    }
    __syncthreads();

    // thread (r0 = tid>>4, c = tid&15): rows r0*8..r0*8+7, chunk slice*16+c.
    // 8 loads issued back-to-back (8-deep MLP), then consumed.
    const int c  = tid & 15;
    const int r0 = tid >> 4;
    const int gc = slice * 16 + c;              // global float4 column 0..127
    const float4* cb4 = (const float4*)codebook;

    float ax = 0.f, ay = 0.f, az = 0.f, aw = 0.f;
    {
        int    idx[8];
        float4 buf[8];
        #pragma unroll
        for (int j = 0; j < 8; j++) idx[j] = s_idx[r0 * 8 + j];
        #pragma unroll
        for (int j = 0; j < 8; j++) buf[j] = cb4[(size_t)idx[j] * 128 + gc];
        #pragma unroll
        for (int j = 0; j < 8; j++) {
            float m = (idx[j] != PAD_V) ? 1.0f : 0.0f;
            ax = fmaf(m, buf[j].x, ax);
            ay = fmaf(m, buf[j].y, ay);
            az = fmaf(m, buf[j].z, az);
            aw = fmaf(m, buf[j].w, aw);
        }
    }
    s_part[r0][c] = make_float4(ax, ay, az, aw);
    __syncthreads();

    if (tid < 16) {
        int cnt = s_cnt[0] + s_cnt[1];
        float inv = (cnt > 0) ? 1.0f / (float)cnt : 0.0f;
        float e0 = 0.f, e1 = 0.f, e2 = 0.f, e3 = 0.f;
        #pragma unroll
        for (int r = 0; r < 16; r++) {
            float4 p = s_part[r][tid];
            e0 += p.x; e1 += p.y; e2 += p.z; e3 += p.w;
        }
        e0 *= inv; e1 *= inv; e2 *= inv; e3 *= inv;
        float4 o;
        o.x = (e0 >= 0.f) ? e0 : a0 * e0;
        o.y = (e1 >= 0.f) ? e1 : a0 * e1;
        o.z = (e2 >= 0.f) ? e2 : a0 * e2;
        o.w = (e3 >= 0.f) ? e3 : a0 * e3;
        ((float4*)x_ws)[(size_t)bag * 128 + slice * 16 + tid] = o;
    }
}

// Kernel 2: 2-layer MLP per bag (weights are L2-resident, <600 KB total).
__global__ __launch_bounds__(256, 8) void mlp_kernel(
    const float* __restrict__ x_ws,
    const float* __restrict__ qW1, const float* __restrict__ qb1,
    const float* __restrict__ qW2, const float* __restrict__ qb2,
    const float* __restrict__ pW1, const float* __restrict__ pb1,
    const float* __restrict__ pW2, const float* __restrict__ pb2,
    const float* __restrict__ qa1p, const float* __restrict__ qa2p,
    const float* __restrict__ pa1p, const float* __restrict__ pa2p,
    float* __restrict__ qh_out, float* __restrict__ ph_out)
{
    const int tid = threadIdx.x;
    const int bag = blockIdx.x;
    const bool is_q = (bag < B_SZ);
    const float *W1, *b1, *W2, *b2;
    float a1, a2;
    float* out;
    int bagl;
    if (is_q) {
        bagl = bag;
        W1 = qW1; b1 = qb1; W2 = qW2; b2 = qb2;
        a1 = *qa1p; a2 = *qa2p;
        out = qh_out;
    } else {
        bagl = bag - B_SZ;
        W1 = pW1; b1 = pb1; W2 = pW2; b2 = pb2;
        a1 = *pa1p; a2 = *pa2p;
        out = ph_out;
    }

    __shared__ float s_x[H1];        // 2 KB
    __shared__ float s_p1[16][H2];   // 4 KB
    __shared__ float s_h1[H2];

    if (tid < 128)
        ((float4*)s_x)[tid] = ((const float4*)x_ws)[(size_t)bag * 128 + tid];
    __syncthreads();

    const int j4 = tid & 15;   // col quad
    const int ch = tid >> 4;   // 0..15 i-chunk

    // layer 1: 32 i's per chunk
    {
        const float4* W1v = (const float4*)W1;
        const int i0 = ch * 32;
        float sx = 0.f, sy = 0.f, sz = 0.f, sw = 0.f;
        #pragma unroll 8
        for (int i = 0; i < 32; i++) {
            float x = s_x[i0 + i];
            float4 w = W1v[(size_t)(i0 + i) * 16 + j4];
            sx = fmaf(x, w.x, sx);
            sy = fmaf(x, w.y, sy);
            sz = fmaf(x, w.z, sz);
            sw = fmaf(x, w.w, sw);
        }
        s_p1[ch][4 * j4 + 0] = sx;
        s_p1[ch][4 * j4 + 1] = sy;
        s_p1[ch][4 * j4 + 2] = sz;
        s_p1[ch][4 * j4 + 3] = sw;
    }
    __syncthreads();
    if (tid < H2) {
        float s = b1[tid];
        #pragma unroll
        for (int r = 0; r < 16; r++) s += s_p1[r][tid];
        s_h1[tid] = (s >= 0.f) ? s : a1 * s;
    }
    __syncthreads();

    // layer 2: 4 i's per chunk
    {
        const float4* W2v = (const float4*)W2;
        const int i0 = ch * 4;
        float sx = 0.f, sy = 0.f, sz = 0.f, sw = 0.f;
        #pragma unroll
        for (int i = 0; i < 4; i++) {
            float x = s_h1[i0 + i];
            float4 w = W2v[(size_t)(i0 + i) * 16 + j4];
            sx = fmaf(x, w.x, sx);
            sy = fmaf(x, w.y, sy);
            sz = fmaf(x, w.z, sz);
            sw = fmaf(x, w.w, sw);
        }
        s_p1[ch][4 * j4 + 0] = sx;
        s_p1[ch][4 * j4 + 1] = sy;
        s_p1[ch][4 * j4 + 2] = sz;
        s_p1[ch][4 * j4 + 3] = sw;
    }
    __syncthreads();
    if (tid < H2) {
        float s = b2[tid];
        #pragma unroll
        for (int r = 0; r < 16; r++) s += s_p1[r][tid];
        s = (s >= 0.f) ? s : a2 * s;
        out[bagl * H2 + tid] = s;
    }
}

// ---------------------------------------------------------------------------
// Kernel 3: one wave per (b,k). Pure dot phase over precompacted hits.
// ---------------------------------------------------------------------------
__global__ __launch_bounds__(64) void text_sim_kernel(
    const float* __restrict__ q_eval, const float* __restrict__ p_eval,
    const float* __restrict__ qh_ws, const float* __restrict__ ph_ws,
    const int* __restrict__ nh_ws, const int* __restrict__ hits_ws,
    const float* __restrict__ ind_ap,
    float* __restrict__ text_out)
{
    const int blk = blockIdx.x;      // (b,k) pair
    const int b    = blk >> 5;
    const int lane = threadIdx.x;    // 0..63

    const float qh = qh_ws[b * H2 + lane];
    const float ph = ph_ws[blk * H2 + lane];
    const int   nh = nh_ws[blk];
    const float ind_a = *ind_ap;

    float local = 0.f;
    for (int hh = 0; hh < nh; hh++) {
        int v = hits_ws[blk * L_SZ + hh];
        float qd = qh * q_eval[(size_t)v * H2 + lane];
        float pd = ph * p_eval[(size_t)v * H2 + lane];
        #pragma unroll
        for (int m = 1; m < 64; m <<= 1) {
            qd += __shfl_xor(qd, m);
            pd += __shfl_xor(pd, m);
        }
        qd = (qd >= 0.f) ? qd : ind_a * qd;
        pd = (pd >= 0.f) ? pd : ind_a * pd;
        local += (qd + 1.f) * (pd + 1.f);
    }
    if (lane == 0) text_out[blk] = local;
}

// ---------------------------------------------------------------------------
// Kernel 4: epilogue — one block per b: max, normalize, sigmoid, distance.
// ---------------------------------------------------------------------------
__global__ __launch_bounds__(64) void epilogue_kernel(
    const float* __restrict__ text_ws,
    const float* __restrict__ qloc, const float* __restrict__ ploc,
    const float* __restrict__ ap, const float* __restrict__ bp,
    const float* __restrict__ cp, const float* __restrict__ dp,
    float* __restrict__ out)
{
    const int b = blockIdx.x;
    const int t = threadIdx.x;
    const int kk = t & 31;

    float ts_raw = text_ws[b * K_SZ + kk];
    float mx = ts_raw;
    #pragma unroll
    for (int m = 1; m < 32; m <<= 1) mx = fmaxf(mx, __shfl_xor(mx, m));

    float qx = qloc[b * 2], qy = qloc[b * 2 + 1];
    float px = ploc[(b * K_SZ + kk) * 2];
    float py = ploc[(b * K_SZ + kk) * 2 + 1];
    float dx = qx - px, dy = qy - py;
    float dist = sqrtf(dx * dx + dy * dy);
    float ds = -logf(dist + 1.0f);

    float ts = (2.0f * ts_raw - mx) / (mx + 1e-6f);
    float A = *ap, Bb = *bp, C = *cp, D = *dp;
    float sig = 1.0f / (1.0f + expf(-(A * ts + Bb)));
    if (t < 32) out[b * K_SZ + kk] = (C - sig) * (ds - D);
}

extern "C" void kernel_launch(void* const* d_in, const int* in_sizes, int n_in,
                              void* d_out, int out_size, void* d_ws, size_t ws_size,
                              hipStream_t stream) {
    const int*   qbf      = (const int*)d_in[0];
    const int*   pbf      = (const int*)d_in[1];
    const float* qloc     = (const float*)d_in[2];
    const float* ploc     = (const float*)d_in[3];
    const float* codebook = (const float*)d_in[4];
    const float* qW1      = (const float*)d_in[5];
    const float* qb1      = (const float*)d_in[6];
    const float* qW2      = (const float*)d_in[7];
    const float* qb2      = (const float*)d_in[8];
    const float* pW1      = (const float*)d_in[9];
    const float* pb1      = (const float*)d_in[10];
    const float* pW2      = (const float*)d_in[11];
    const float* pb2      = (const float*)d_in[12];
    const float* q_eval   = (const float*)d_in[13];
    const float* p_eval   = (const float*)d_in[14];
    const float* qa0      = (const float*)d_in[15];
    const float* qa1      = (const float*)d_in[16];
    const float* qa2      = (const float*)d_in[17];
    const float* pa0      = (const float*)d_in[18];
    const float* pa1      = (const float*)d_in[19];
    const float* pa2      = (const float*)d_in[20];
    const float* ind_a    = (const float*)d_in[21];
    const float* a        = (const float*)d_in[22];
    const float* bsc      = (const float*)d_in[23];
    const float* c        = (const float*)d_in[24];
    const float* d        = (const float*)d_in[25];

    float* qh   = (float*)d_ws;                   // 32*64
    float* ph   = qh + B_SZ * H2;                 // 1024*64
    float* text = ph + B_SZ * K_SZ * H2;          // 1024
    int*   nh   = (int*)(text + B_SZ * K_SZ);     // 1024
    int*   hits = nh + B_SZ * K_SZ;               // 1024*128
    float* x_ws = (float*)(hits + B_SZ * K_SZ * L_SZ);  // 1056*512 (16B-aligned)

    gather_kernel<<<GATHER_BLOCKS + ISECT2_BLOCKS, 256, 0, stream>>>(
        qbf, pbf, codebook, qa0, pa0, x_ws, nh, hits);

    mlp_kernel<<<NBAGS, 256, 0, stream>>>(
        x_ws, qW1, qb1, qW2, qb2, pW1, pb1, pW2, pb2,
        qa1, qa2, pa1, pa2, qh, ph);

    text_sim_kernel<<<B_SZ * K_SZ, 64, 0, stream>>>(
        q_eval, p_eval, qh, ph, nh, hits, ind_a, text);

    epilogue_kernel<<<B_SZ, 64, 0, stream>>>(
        text, qloc, ploc, a, bsc, c, d, (float*)d_out);
}

// Round 11
// 139.438 us; speedup vs baseline: 1.1982x; 1.0411x over previous
//
#include <hip/hip_runtime.h>

#define PAD_V 8192
#define H1 512
#define H2 64
#define B_SZ 32
#define K_SZ 32
#define L_SZ 128
#define NBAGS (B_SZ + B_SZ * K_SZ)            // 1056
#define NSLICE 8                              // codebook column slices (1 per XCD)
#define GATHER_BLOCKS (NBAGS * NSLICE)        // 8448 (pure gather now)
#define MLP4_BLOCKS (NBAGS / 4)               // 264: 4 bags per block
#define ISECT2_BLOCKS ((B_SZ * K_SZ) / 2)     // 512: 2 pairs per block (in k2 grid)

// ---------------------------------------------------------------------------
// R8. R7 (column-sliced gather, verified −12 us): each XCD's L2 pinned to a
// 2.1MB codebook column set via slice = blockIdx % 8. Kept intact.
// R8 changes (low-risk bundle):
//  (1) isect role moved from gather grid to mlp grid — stops competing with
//      the 8448 gather blocks, overlaps the tiny mlp instead.
//  (2) mlp 4 bags/block: weight L2 traffic 139MB -> 35MB. (L2-BW-bound
//      regime — amortization correct here, unlike R5's latency-bound gather.)
//  (3) text_sim 2-deep prefetch: next hit's eval rows load under the
//      shuffle reduce.
// NOTE (R4): no device-atomic cross-kernel fusion (+22 us). R5: no multi-bag
// in latency-bound gather. R6: gather MLP-depth is not the limiter.
// ---------------------------------------------------------------------------

// Kernel 1: pure column-sliced gather.
__global__ __launch_bounds__(256, 4) void gather_kernel(
    const int* __restrict__ qbf, const int* __restrict__ pbf,
    const float* __restrict__ codebook,
    const float* __restrict__ qa0p, const float* __restrict__ pa0p,
    float* __restrict__ x_ws)
{
    const int tid = threadIdx.x;
    const int slice = blockIdx.x & (NSLICE - 1);
    const int bag   = blockIdx.x >> 3;          // 0..1055
    const bool is_q = (bag < B_SZ);
    const int* idx_base = is_q ? qbf : pbf;
    const int  bagl     = is_q ? bag : (bag - B_SZ);
    const float a0      = is_q ? *qa0p : *pa0p;

    __shared__ int   s_idx[L_SZ];
    __shared__ int   s_cnt[2];
    __shared__ float4 s_part[16][16];           // 4 KB

    if (tid < L_SZ) {
        int v = idx_base[bagl * L_SZ + tid];
        s_idx[tid] = v;
        unsigned long long bal = __ballot(v != PAD_V);
        if ((tid & 63) == 0) s_cnt[tid >> 6] = __popcll(bal);
    }
    __syncthreads();

    // thread (r0 = tid>>4, c = tid&15): rows r0*8..r0*8+7, chunk slice*16+c.
    const int c  = tid & 15;
    const int r0 = tid >> 4;
    const int gc = slice * 16 + c;              // global float4 column 0..127
    const float4* cb4 = (const float4*)codebook;

    float ax = 0.f, ay = 0.f, az = 0.f, aw = 0.f;
    {
        int    idx[8];
        float4 buf[8];
        #pragma unroll
        for (int j = 0; j < 8; j++) idx[j] = s_idx[r0 * 8 + j];
        #pragma unroll
        for (int j = 0; j < 8; j++) buf[j] = cb4[(size_t)idx[j] * 128 + gc];
        #pragma unroll
        for (int j = 0; j < 8; j++) {
            float m = (idx[j] != PAD_V) ? 1.0f : 0.0f;
            ax = fmaf(m, buf[j].x, ax);
            ay = fmaf(m, buf[j].y, ay);
            az = fmaf(m, buf[j].z, az);
            aw = fmaf(m, buf[j].w, aw);
        }
    }
    s_part[r0][c] = make_float4(ax, ay, az, aw);
    __syncthreads();

    if (tid < 16) {
        int cnt = s_cnt[0] + s_cnt[1];
        float inv = (cnt > 0) ? 1.0f / (float)cnt : 0.0f;
        float e0 = 0.f, e1 = 0.f, e2 = 0.f, e3 = 0.f;
        #pragma unroll
        for (int r = 0; r < 16; r++) {
            float4 p = s_part[r][tid];
            e0 += p.x; e1 += p.y; e2 += p.z; e3 += p.w;
        }
        e0 *= inv; e1 *= inv; e2 *= inv; e3 *= inv;
        float4 o;
        o.x = (e0 >= 0.f) ? e0 : a0 * e0;
        o.y = (e1 >= 0.f) ? e1 : a0 * e1;
        o.z = (e2 >= 0.f) ? e2 : a0 * e2;
        o.w = (e3 >= 0.f) ? e3 : a0 * e3;
        ((float4*)x_ws)[(size_t)bag * 128 + slice * 16 + tid] = o;
    }
}

// Kernel 2: MLP (4 bags/block, weights loaded once per block) + isect role.
__global__ __launch_bounds__(256, 4) void mlp_isect_kernel(
    const float* __restrict__ x_ws,
    const int* __restrict__ qbf, const int* __restrict__ pbf,
    const float* __restrict__ qW1, const float* __restrict__ qb1,
    const float* __restrict__ qW2, const float* __restrict__ qb2,
    const float* __restrict__ pW1, const float* __restrict__ pb1,
    const float* __restrict__ pW2, const float* __restrict__ pb2,
    const float* __restrict__ qa1p, const float* __restrict__ qa2p,
    const float* __restrict__ pa1p, const float* __restrict__ pa2p,
    float* __restrict__ qh_out, float* __restrict__ ph_out,
    int* __restrict__ nh_ws, int* __restrict__ hits_ws)
{
    const int tid = threadIdx.x;

    // ---- role B: intersection (2 pairs per 256-thr block) ----
    if (blockIdx.x >= MLP4_BLOCKS) {
        __shared__ unsigned int bm2[2][256];   // 2 KB
        __shared__ int s_nh2[2];
        __shared__ int s_hit2[2][L_SZ];        // 1 KB

        const int pair0 = (blockIdx.x - MLP4_BLOCKS) * 2;
        const int sub = tid >> 7;              // 0..1
        const int t   = tid & 127;
        const int pair = pair0 + sub;
        const int b = pair >> 5;

        bm2[sub][t] = 0u; bm2[sub][t + 128] = 0u;
        if (t == 0) s_nh2[sub] = 0;
        __syncthreads();

        int pv = pbf[pair * L_SZ + t];
        if ((unsigned)pv < (unsigned)PAD_V)
            atomicOr(&bm2[sub][pv >> 5], 1u << (pv & 31));
        __syncthreads();

        int v = qbf[b * L_SZ + t];
        bool hit = ((unsigned)v < (unsigned)PAD_V) &&
                   ((bm2[sub][v >> 5] >> (v & 31)) & 1u);
        if (hit) {
            int pos = atomicAdd(&s_nh2[sub], 1);
            s_hit2[sub][pos] = v;
        }
        __syncthreads();

        if (t == 0) nh_ws[pair] = s_nh2[sub];
        if (t < s_nh2[sub]) hits_ws[pair * L_SZ + t] = s_hit2[sub][t];
        return;
    }

    // ---- role A: MLP, 4 bags per block (all same type: q blocks 0..7) ----
    const int m = blockIdx.x;
    const bool is_q = (m < (B_SZ / 4));
    const int bag0 = m * 4;                    // global bag 4m..4m+3
    const float *W1, *b1, *W2, *b2;
    float a1, a2;
    float* out;
    int bagl0;
    if (is_q) {
        bagl0 = bag0;
        W1 = qW1; b1 = qb1; W2 = qW2; b2 = qb2;
        a1 = *qa1p; a2 = *qa2p;
        out = qh_out;
    } else {
        bagl0 = bag0 - B_SZ;
        W1 = pW1; b1 = pb1; W2 = pW2; b2 = pb2;
        a1 = *pa1p; a2 = *pa2p;
        out = ph_out;
    }

    __shared__ float s_x[4][H1];       // 8 KB
    __shared__ float s_p1[4][16][H2];  // 16 KB
    __shared__ float s_h1[4][H2];      // 1 KB

    {
        const float4* x4 = (const float4*)x_ws;
        float4* sx4 = (float4*)&s_x[0][0];
        sx4[tid]       = x4[(size_t)bag0 * 128 + tid];
        sx4[tid + 256] = x4[(size_t)bag0 * 128 + tid + 256];
    }
    __syncthreads();

    const int j4 = tid & 15;   // col quad
    const int ch = tid >> 4;   // 0..15 i-chunk

    // layer 1: 32 i's per chunk; each weight float4 applied to 4 bags
    {
        const float4* W1v = (const float4*)W1;
        const int i0 = ch * 32;
        float4 A0 = make_float4(0.f,0.f,0.f,0.f);
        float4 A1 = make_float4(0.f,0.f,0.f,0.f);
        float4 A2 = make_float4(0.f,0.f,0.f,0.f);
        float4 A3 = make_float4(0.f,0.f,0.f,0.f);
        #pragma unroll 8
        for (int i = 0; i < 32; i++) {
            float4 w = W1v[(size_t)(i0 + i) * 16 + j4];
            float x0 = s_x[0][i0 + i];
            float x1 = s_x[1][i0 + i];
            float x2 = s_x[2][i0 + i];
            float x3 = s_x[3][i0 + i];
            A0.x = fmaf(x0, w.x, A0.x); A0.y = fmaf(x0, w.y, A0.y);
            A0.z = fmaf(x0, w.z, A0.z); A0.w = fmaf(x0, w.w, A0.w);
            A1.x = fmaf(x1, w.x, A1.x); A1.y = fmaf(x1, w.y, A1.y);
            A1.z = fmaf(x1, w.z, A1.z); A1.w = fmaf(x1, w.w, A1.w);
            A2.x = fmaf(x2, w.x, A2.x); A2.y = fmaf(x2, w.y, A2.y);
            A2.z = fmaf(x2, w.z, A2.z); A2.w = fmaf(x2, w.w, A2.w);
            A3.x = fmaf(x3, w.x, A3.x); A3.y = fmaf(x3, w.y, A3.y);
            A3.z = fmaf(x3, w.z, A3.z); A3.w = fmaf(x3, w.w, A3.w);
        }
        s_p1[0][ch][4*j4+0] = A0.x; s_p1[0][ch][4*j4+1] = A0.y;
        s_p1[0][ch][4*j4+2] = A0.z; s_p1[0][ch][4*j4+3] = A0.w;
        s_p1[1][ch][4*j4+0] = A1.x; s_p1[1][ch][4*j4+1] = A1.y;
        s_p1[1][ch][4*j4+2] = A1.z; s_p1[1][ch][4*j4+3] = A1.w;
        s_p1[2][ch][4*j4+0] = A2.x; s_p1[2][ch][4*j4+1] = A2.y;
        s_p1[2][ch][4*j4+2] = A2.z; s_p1[2][ch][4*j4+3] = A2.w;
        s_p1[3][ch][4*j4+0] = A3.x; s_p1[3][ch][4*j4+1] = A3.y;
        s_p1[3][ch][4*j4+2] = A3.z; s_p1[3][ch][4*j4+3] = A3.w;
    }
    __syncthreads();
    {
        const int bg = tid >> 6, col = tid & 63;   // 4 bags x 64 cols = 256
        float s = b1[col];
        #pragma unroll
        for (int r = 0; r < 16; r++) s += s_p1[bg][r][col];
        s_h1[bg][col] = (s >= 0.f) ? s : a1 * s;
    }
    __syncthreads();

    // layer 2: 4 i's per chunk
    {
        const float4* W2v = (const float4*)W2;
        const int i0 = ch * 4;
        float4 A0 = make_float4(0.f,0.f,0.f,0.f);
        float4 A1 = make_float4(0.f,0.f,0.f,0.f);
        float4 A2 = make_float4(0.f,0.f,0.f,0.f);
        float4 A3 = make_float4(0.f,0.f,0.f,0.f);
        #pragma unroll
        for (int i = 0; i < 4; i++) {
            float4 w = W2v[(size_t)(i0 + i) * 16 + j4];
            float x0 = s_h1[0][i0 + i];
            float x1 = s_h1[1][i0 + i];
            float x2 = s_h1[2][i0 + i];
            float x3 = s_h1[3][i0 + i];
            A0.x = fmaf(x0, w.x, A0.x); A0.y = fmaf(x0, w.y, A0.y);
            A0.z = fmaf(x0, w.z, A0.z); A0.w = fmaf(x0, w.w, A0.w);
            A1.x = fmaf(x1, w.x, A1.x); A1.y = fmaf(x1, w.y, A1.y);
            A1.z = fmaf(x1, w.z, A1.z); A1.w = fmaf(x1, w.w, A1.w);
            A2.x = fmaf(x2, w.x, A2.x); A2.y = fmaf(x2, w.y, A2.y);
            A2.z = fmaf(x2, w.z, A2.z); A2.w = fmaf(x2, w.w, A2.w);
            A3.x = fmaf(x3, w.x, A3.x); A3.y = fmaf(x3, w.y, A3.y);
            A3.z = fmaf(x3, w.z, A3.z); A3.w = fmaf(x3, w.w, A3.w);
        }
        s_p1[0][ch][4*j4+0] = A0.x; s_p1[0][ch][4*j4+1] = A0.y;
        s_p1[0][ch][4*j4+2] = A0.z; s_p1[0][ch][4*j4+3] = A0.w;
        s_p1[1][ch][4*j4+0] = A1.x; s_p1[1][ch][4*j4+1] = A1.y;
        s_p1[1][ch][4*j4+2] = A1.z; s_p1[1][ch][4*j4+3] = A1.w;
        s_p1[2][ch][4*j4+0] = A2.x; s_p1[2][ch][4*j4+1] = A2.y;
        s_p1[2][ch][4*j4+2] = A2.z; s_p1[2][ch][4*j4+3] = A2.w;
        s_p1[3][ch][4*j4+0] = A3.x; s_p1[3][ch][4*j4+1] = A3.y;
        s_p1[3][ch][4*j4+2] = A3.z; s_p1[3][ch][4*j4+3] = A3.w;
    }
    __syncthreads();
    {
        const int bg = tid >> 6, col = tid & 63;
        float s = b2[col];
        #pragma unroll
        for (int r = 0; r < 16; r++) s += s_p1[bg][r][col];
        s = (s >= 0.f) ? s : a2 * s;
        out[(bagl0 + bg) * H2 + col] = s;
    }
}

// ---------------------------------------------------------------------------
// Kernel 3: one wave per (b,k), 2-deep prefetch over precompacted hits.
// ---------------------------------------------------------------------------
__global__ __launch_bounds__(64) void text_sim_kernel(
    const float* __restrict__ q_eval, const float* __restrict__ p_eval,
    const float* __restrict__ qh_ws, const float* __restrict__ ph_ws,
    const int* __restrict__ nh_ws, const int* __restrict__ hits_ws,
    const float* __restrict__ ind_ap,
    float* __restrict__ text_out)
{
    const int blk = blockIdx.x;      // (b,k) pair
    const int b    = blk >> 5;
    const int lane = threadIdx.x;    // 0..63

    const float qh = qh_ws[b * H2 + lane];
    const float ph = ph_ws[blk * H2 + lane];
    const int   nh = nh_ws[blk];
    const float ind_a = *ind_ap;

    float local = 0.f;
    if (nh > 0) {
        int v = hits_ws[blk * L_SZ];
        float qe = q_eval[(size_t)v * H2 + lane];
        float pe = p_eval[(size_t)v * H2 + lane];
        for (int hh = 0; hh < nh; hh++) {
            float qe_n = 0.f, pe_n = 0.f;
            if (hh + 1 < nh) {                    // uniform branch per wave
                int vn = hits_ws[blk * L_SZ + hh + 1];
                qe_n = q_eval[(size_t)vn * H2 + lane];
                pe_n = p_eval[(size_t)vn * H2 + lane];
            }
            float qd = qh * qe;
            float pd = ph * pe;
            #pragma unroll
            for (int m = 1; m < 64; m <<= 1) {
                qd += __shfl_xor(qd, m);
                pd += __shfl_xor(pd, m);
            }
            qd = (qd >= 0.f) ? qd : ind_a * qd;
            pd = (pd >= 0.f) ? pd : ind_a * pd;
            local += (qd + 1.f) * (pd + 1.f);
            qe = qe_n; pe = pe_n;
        }
    }
    if (lane == 0) text_out[blk] = local;
}

// ---------------------------------------------------------------------------
// Kernel 4: epilogue — one block per b: max, normalize, sigmoid, distance.
// ---------------------------------------------------------------------------
__global__ __launch_bounds__(64) void epilogue_kernel(
    const float* __restrict__ text_ws,
    const float* __restrict__ qloc, const float* __restrict__ ploc,
    const float* __restrict__ ap, const float* __restrict__ bp,
    const float* __restrict__ cp, const float* __restrict__ dp,
    float* __restrict__ out)
{
    const int b = blockIdx.x;
    const int t = threadIdx.x;
    const int kk = t & 31;

    float ts_raw = text_ws[b * K_SZ + kk];
    float mx = ts_raw;
    #pragma unroll
    for (int m = 1; m < 32; m <<= 1) mx = fmaxf(mx, __shfl_xor(mx, m));

    float qx = qloc[b * 2], qy = qloc[b * 2 + 1];
    float px = ploc[(b * K_SZ + kk) * 2];
    float py = ploc[(b * K_SZ + kk) * 2 + 1];
    float dx = qx - px, dy = qy - py;
    float dist = sqrtf(dx * dx + dy * dy);
    float ds = -logf(dist + 1.0f);

    float ts = (2.0f * ts_raw - mx) / (mx + 1e-6f);
    float A = *ap, Bb = *bp, C = *cp, D = *dp;
    float sig = 1.0f / (1.0f + expf(-(A * ts + Bb)));
    if (t < 32) out[b * K_SZ + kk] = (C - sig) * (ds - D);
}

extern "C" void kernel_launch(void* const* d_in, const int* in_sizes, int n_in,
                              void* d_out, int out_size, void* d_ws, size_t ws_size,
                              hipStream_t stream) {
    const int*   qbf      = (const int*)d_in[0];
    const int*   pbf      = (const int*)d_in[1];
    const float* qloc     = (const float*)d_in[2];
    const float* ploc     = (const float*)d_in[3];
    const float* codebook = (const float*)d_in[4];
    const float* qW1      = (const float*)d_in[5];
    const float* qb1      = (const float*)d_in[6];
    const float* qW2      = (const float*)d_in[7];
    const float* qb2      = (const float*)d_in[8];
    const float* pW1      = (const float*)d_in[9];
    const float* pb1      = (const float*)d_in[10];
    const float* pW2      = (const float*)d_in[11];
    const float* pb2      = (const float*)d_in[12];
    const float* q_eval   = (const float*)d_in[13];
    const float* p_eval   = (const float*)d_in[14];
    const float* qa0      = (const float*)d_in[15];
    const float* qa1      = (const float*)d_in[16];
    const float* qa2      = (const float*)d_in[17];
    const float* pa0      = (const float*)d_in[18];
    const float* pa1      = (const float*)d_in[19];
    const float* pa2      = (const float*)d_in[20];
    const float* ind_a    = (const float*)d_in[21];
    const float* a        = (const float*)d_in[22];
    const float* bsc      = (const float*)d_in[23];
    const float* c        = (const float*)d_in[24];
    const float* d        = (const float*)d_in[25];

    float* qh   = (float*)d_ws;                   // 32*64
    float* ph   = qh + B_SZ * H2;                 // 1024*64
    float* text = ph + B_SZ * K_SZ * H2;          // 1024
    int*   nh   = (int*)(text + B_SZ * K_SZ);     // 1024
    int*   hits = nh + B_SZ * K_SZ;               // 1024*128
    float* x_ws = (float*)(hits + B_SZ * K_SZ * L_SZ);  // 1056*512 (16B-aligned)

    gather_kernel<<<GATHER_BLOCKS, 256, 0, stream>>>(
        qbf, pbf, codebook, qa0, pa0, x_ws);

    mlp_isect_kernel<<<MLP4_BLOCKS + ISECT2_BLOCKS, 256, 0, stream>>>(
        x_ws, qbf, pbf,
        qW1, qb1, qW2, qb2, pW1, pb1, pW2, pb2,
        qa1, qa2, pa1, pa2, qh, ph, nh, hits);

    text_sim_kernel<<<B_SZ * K_SZ, 64, 0, stream>>>(
        q_eval, p_eval, qh, ph, nh, hits, ind_a, text);

    epilogue_kernel<<<B_SZ, 64, 0, stream>>>(
        text, qloc, ploc, a, bsc, c, d, (float*)d_out);
}